// Round 2
// baseline (177.332 us; speedup 1.0000x reference)
//
#include <hip/hip_runtime.h>

typedef _Float16 half8_t __attribute__((ext_vector_type(8)));
typedef _Float16 half4_t __attribute__((ext_vector_type(4)));
typedef float    float4_t __attribute__((ext_vector_type(4)));

// ---------------- ws layout ----------------
// [0, 55296)        WqkvT  f16  [288][96]   WqkvT[f][k] = W_qkv[k][f]
// [55296, 73728)    WoutT  f16  [96][96]    WoutT[f][k] = W_out[k][f]
// [73728, 77824)    biasT  f32  [4][16][16] biasT[m][j][i] = bias_variant_m[i][j]
#define WOUTT_OFF_H 27648   // in f16 elements
#define BIAST_OFF_B 73728   // bytes

__global__ void prep_kernel(const float* __restrict__ Wqkv,
                            const float* __restrict__ Wout,
                            const float* __restrict__ pos,
                            _Float16* __restrict__ wqkvT,
                            _Float16* __restrict__ woutT,
                            float* __restrict__ biasT) {
  int idx = blockIdx.x * 256 + threadIdx.x;
  if (idx < 288 * 96) {
    int f = idx / 96, k = idx % 96;
    wqkvT[idx] = (_Float16)Wqkv[k * 288 + f];
  } else if (idx < 288 * 96 + 96 * 96) {
    int t = idx - 288 * 96;
    int f = t / 96, k = t % 96;
    woutT[t] = (_Float16)Wout[k * 96 + f];
  } else if (idx < 288 * 96 + 96 * 96 + 1024) {
    int t = idx - (288 * 96 + 96 * 96);
    int m = t >> 8, j = (t >> 4) & 15, i = t & 15;   // store [j][i] = bias[i][j]
    int xi = i >> 2, yi = i & 3, xj = j >> 2, yj = j & 3;
    // bias[i][j] = pos[idx[j] - idx[i] + 3]  (key minus query!)
    float v = pos[(xj - xi + 3) * 7 + (yj - yi + 3)];
    if ((m & 1) && ((i >= 8) != (j >= 8))) v -= 1e9f;      // ul mask (last window row)
    if ((m & 2) && ((yi >= 2) != (yj >= 2))) v -= 1e9f;    // lr mask (last window col)
    biasT[t] = v;
  }
}

// ---------------- per-window LDS layout (f16 elements) ----------------
// QK: [16 tok][200]  feats 0..191 (q:0..95, k:96..191)      -> 3200
// VT: [96 vfeat][20] tokens 0..15                           -> 1920
// OB: [16 tok][104]  attn-out feats 0..95                   -> 1664
#define W_LDS 6784
#define QK_STRIDE 200
#define VT_STRIDE 20
#define OB_STRIDE 104
#define VT_OFF 3200
#define OB_OFF 5120

__global__ __launch_bounds__(256, 2)
void swin_fused(const float* __restrict__ x,
                const _Float16* __restrict__ wqkvT,
                const _Float16* __restrict__ woutT,
                const float* __restrict__ biasT,
                const float* __restrict__ b_out,
                float* __restrict__ out) {
  __shared__ _Float16 lds[4 * W_LDS];
  const int tid  = threadIdx.x;
  const int wave = tid >> 6;
  const int lane = tid & 63;
  const int l15  = lane & 15;
  const int g    = (lane >> 4) & 3;
  const int ty = l15 >> 2, tx = l15 & 3;

  const int blk   = blockIdx.x;
  const int batch = blk / 49;
  const int wset  = blk % 49;     // 16 windows: wset*16 .. +15

  // hoist WoutT fragments (A-operand of GEMM3): row = outfeat mt*16+l15, k = 32kt+8g..
  half8_t woutf[6][3];
#pragma unroll
  for (int mt = 0; mt < 6; ++mt)
#pragma unroll
    for (int kt = 0; kt < 3; ++kt)
      woutf[mt][kt] = *(const half8_t*)&woutT[(mt * 16 + l15) * 96 + kt * 32 + g * 8];

  for (int grp = 0; grp < 4; ++grp) {
    const int wid0 = wset * 16 + grp * 4;

    // ---- x fragments for the 4 windows of this group (shift folded into address)
    half8_t xf[4][3];
#pragma unroll
    for (int wi = 0; wi < 4; ++wi) {
      int wid = wid0 + wi;
      int wrow = wid / 28, wcol = wid % 28;
      int p = wrow * 4 + ty + 2; if (p >= 112) p -= 112;
      int q = wcol * 4 + tx + 2; if (q >= 112) q -= 112;
      const float* xr = x + (((size_t)batch * 112 + p) * 112 + q) * 96 + g * 8;
#pragma unroll
      for (int kt = 0; kt < 3; ++kt) {
        float4_t a = *(const float4_t*)(xr + kt * 32);
        float4_t b = *(const float4_t*)(xr + kt * 32 + 4);
        half8_t h;
        h[0] = (_Float16)a[0]; h[1] = (_Float16)a[1];
        h[2] = (_Float16)a[2]; h[3] = (_Float16)a[3];
        h[4] = (_Float16)b[0]; h[5] = (_Float16)b[1];
        h[6] = (_Float16)b[2]; h[7] = (_Float16)b[3];
        xf[wi][kt] = h;
      }
    }

    // ---- GEMM1: feature tiles split across waves (W-frags shared over 4 windows)
    const int t0 = (wave * 18) >> 2;
    const int t1 = ((wave + 1) * 18) >> 2;
    for (int f = t0; f < t1; ++f) {
      const _Float16* wrow_p = &wqkvT[(f * 16 + l15) * 96 + g * 8];
      half8_t wf0 = *(const half8_t*)(wrow_p);
      half8_t wf1 = *(const half8_t*)(wrow_p + 32);
      half8_t wf2 = *(const half8_t*)(wrow_p + 64);
#pragma unroll
      for (int wi = 0; wi < 4; ++wi) {
        float4_t acc = {0.f, 0.f, 0.f, 0.f};
        half4_t hh;
        if (f < 12) {
          // D = WqkvT_slice @ x^T : row = feat f*16+4g+i, col = tok l15
          acc = __builtin_amdgcn_mfma_f32_16x16x32_f16(wf0, xf[wi][0], acc, 0, 0, 0);
          acc = __builtin_amdgcn_mfma_f32_16x16x32_f16(wf1, xf[wi][1], acc, 0, 0, 0);
          acc = __builtin_amdgcn_mfma_f32_16x16x32_f16(wf2, xf[wi][2], acc, 0, 0, 0);
          hh[0] = (_Float16)acc[0]; hh[1] = (_Float16)acc[1];
          hh[2] = (_Float16)acc[2]; hh[3] = (_Float16)acc[3];
          *(half4_t*)&lds[wi * W_LDS + l15 * QK_STRIDE + f * 16 + g * 4] = hh;
        } else {
          // D = x @ W_slice : row = tok 4g+i, col = feat -> vT[vfeat][tok]
          acc = __builtin_amdgcn_mfma_f32_16x16x32_f16(xf[wi][0], wf0, acc, 0, 0, 0);
          acc = __builtin_amdgcn_mfma_f32_16x16x32_f16(xf[wi][1], wf1, acc, 0, 0, 0);
          acc = __builtin_amdgcn_mfma_f32_16x16x32_f16(xf[wi][2], wf2, acc, 0, 0, 0);
          hh[0] = (_Float16)acc[0]; hh[1] = (_Float16)acc[1];
          hh[2] = (_Float16)acc[2]; hh[3] = (_Float16)acc[3];
          *(half4_t*)&lds[wi * W_LDS + VT_OFF + ((f - 12) * 16 + l15) * VT_STRIDE + g * 4] = hh;
        }
      }
    }
    __syncthreads();

    // ---- attention: wave w owns window w of the group
    {
      const int wi = wave;
      const int wid = wid0 + wi;
      const int wrow = wid / 28, wcol = wid % 28;
      const _Float16* qk = &lds[wi * W_LDS];
      const _Float16* vt = &lds[wi * W_LDS + VT_OFF];
      _Float16* ob = &lds[wi * W_LDS + OB_OFF];
      const int var = (wrow == 27 ? 1 : 0) + (wcol == 27 ? 2 : 0);
      const float* bt = biasT + var * 256 + g * 64 + l15;   // biasT[var][j=4g+i'][i=l15]
#pragma unroll
      for (int h = 0; h < 3; ++h) {
        // dots^T = K @ Q^T  (one 16x16x32 mfma; K = head_dim = 32)
        half8_t ak = *(const half8_t*)&qk[l15 * QK_STRIDE + 96 + h * 32 + g * 8];
        half8_t bq = *(const half8_t*)&qk[l15 * QK_STRIDE +      h * 32 + g * 8];
        float4_t dd = {0.f, 0.f, 0.f, 0.f};
        dd = __builtin_amdgcn_mfma_f32_16x16x32_f16(ak, bq, dd, 0, 0, 0);
        const float scale = 0.17677669529663687f;  // 32^-0.5
        float dv0 = dd[0] * scale + bt[0];
        float dv1 = dd[1] * scale + bt[16];
        float dv2 = dd[2] * scale + bt[32];
        float dv3 = dd[3] * scale + bt[48];
        // softmax over keys j (4 regs + lane-groups): col i fixed per lane
        float mx = fmaxf(fmaxf(dv0, dv1), fmaxf(dv2, dv3));
        mx = fmaxf(mx, __shfl_xor(mx, 16, 64));
        mx = fmaxf(mx, __shfl_xor(mx, 32, 64));
        float p0 = __expf(dv0 - mx), p1 = __expf(dv1 - mx);
        float p2 = __expf(dv2 - mx), p3 = __expf(dv3 - mx);
        float s = p0 + p1 + p2 + p3;
        s += __shfl_xor(s, 16, 64);
        s += __shfl_xor(s, 32, 64);
        float r = 1.0f / s;
        half4_t pb;   // P^T in D-layout == valid B-operand of 16x16x16 mfma
        pb[0] = (_Float16)(p0 * r); pb[1] = (_Float16)(p1 * r);
        pb[2] = (_Float16)(p2 * r); pb[3] = (_Float16)(p3 * r);
#pragma unroll
        for (int db = 0; db < 2; ++db) {
          // out^T[dblock] = v^T[dblock] @ P^T   (16x16, K=16 tokens)
          half4_t av = *(const half4_t*)&vt[(h * 32 + db * 16 + l15) * VT_STRIDE + g * 4];
          float4_t o = {0.f, 0.f, 0.f, 0.f};
          o = __builtin_amdgcn_mfma_f32_16x16x16f16(av, pb, o, 0, 0, 0);
          half4_t oh;
          oh[0] = (_Float16)o[0]; oh[1] = (_Float16)o[1];
          oh[2] = (_Float16)o[2]; oh[3] = (_Float16)o[3];
          *(half4_t*)&ob[l15 * OB_STRIDE + h * 32 + db * 16 + g * 4] = oh;
        }
      }
    }
    __syncthreads();

    // ---- GEMM3: y = WoutT @ out^T + b, store with inverse roll folded in
    {
      const int wi = wave;
      const int wid = wid0 + wi;
      const int wrow = wid / 28, wcol = wid % 28;
      const _Float16* ob = &lds[wi * W_LDS + OB_OFF];
      half8_t bf0 = *(const half8_t*)&ob[l15 * OB_STRIDE +      g * 8];
      half8_t bf1 = *(const half8_t*)&ob[l15 * OB_STRIDE + 32 + g * 8];
      half8_t bf2 = *(const half8_t*)&ob[l15 * OB_STRIDE + 64 + g * 8];
      int p = wrow * 4 + ty + 2; if (p >= 112) p -= 112;
      int q = wcol * 4 + tx + 2; if (q >= 112) q -= 112;
      float* orow = out + (((size_t)batch * 112 + p) * 112 + q) * 96;
#pragma unroll
      for (int mt = 0; mt < 6; ++mt) {
        float4_t acc = {0.f, 0.f, 0.f, 0.f};
        acc = __builtin_amdgcn_mfma_f32_16x16x32_f16(woutf[mt][0], bf0, acc, 0, 0, 0);
        acc = __builtin_amdgcn_mfma_f32_16x16x32_f16(woutf[mt][1], bf1, acc, 0, 0, 0);
        acc = __builtin_amdgcn_mfma_f32_16x16x32_f16(woutf[mt][2], bf2, acc, 0, 0, 0);
        float4_t bb = *(const float4_t*)&b_out[mt * 16 + g * 4];
        acc[0] += bb[0]; acc[1] += bb[1]; acc[2] += bb[2]; acc[3] += bb[3];
        *(float4_t*)&orow[mt * 16 + g * 4] = acc;
      }
    }
    __syncthreads();
  }
}

extern "C" void kernel_launch(void* const* d_in, const int* in_sizes, int n_in,
                              void* d_out, int out_size, void* d_ws, size_t ws_size,
                              hipStream_t stream) {
  const float* x    = (const float*)d_in[0];
  const float* Wqkv = (const float*)d_in[1];
  const float* pos  = (const float*)d_in[2];
  const float* Wout = (const float*)d_in[3];
  const float* bout = (const float*)d_in[4];
  char* ws = (char*)d_ws;
  _Float16* wqkvT = (_Float16*)ws;
  _Float16* woutT = ((_Float16*)ws) + WOUTT_OFF_H;
  float* biasT = (float*)(ws + BIAST_OFF_B);

  prep_kernel<<<148, 256, 0, stream>>>(Wqkv, Wout, pos, wqkvT, woutT, biasT);
  swin_fused<<<1568, 256, 0, stream>>>(x, wqkvT, woutT, biasT, bout, (float*)d_out);
}

// Round 3
// 155.586 us; speedup vs baseline: 1.1398x; 1.1398x over previous
//
#include <hip/hip_runtime.h>

typedef _Float16 half8_t __attribute__((ext_vector_type(8)));
typedef _Float16 half4_t __attribute__((ext_vector_type(4)));
typedef float    float4_t __attribute__((ext_vector_type(4)));

// ---------------- ws layout ----------------
// [0, 55296)        WqkvT  f16  [288][96]   WqkvT[f][k] = W_qkv[k][f]
// [55296, 73728)    WoutT  f16  [96][96]    WoutT[f][k] = W_out[k][f]
// [73728, 77824)    biasT  f32  [4][16][16] biasT[m][j][i] = bias_variant_m[i][j]
#define WOUTT_OFF_H 27648   // in f16 elements
#define BIAST_OFF_B 73728   // bytes

__global__ void prep_kernel(const float* __restrict__ Wqkv,
                            const float* __restrict__ Wout,
                            const float* __restrict__ pos,
                            _Float16* __restrict__ wqkvT,
                            _Float16* __restrict__ woutT,
                            float* __restrict__ biasT) {
  int idx = blockIdx.x * 256 + threadIdx.x;
  if (idx < 288 * 96) {
    int f = idx / 96, k = idx % 96;
    wqkvT[idx] = (_Float16)Wqkv[k * 288 + f];
  } else if (idx < 288 * 96 + 96 * 96) {
    int t = idx - 288 * 96;
    int f = t / 96, k = t % 96;
    woutT[t] = (_Float16)Wout[k * 96 + f];
  } else if (idx < 288 * 96 + 96 * 96 + 1024) {
    int t = idx - (288 * 96 + 96 * 96);
    int m = t >> 8, j = (t >> 4) & 15, i = t & 15;   // store [j][i] = bias[i][j]
    int xi = i >> 2, yi = i & 3, xj = j >> 2, yj = j & 3;
    // bias[i][j] = pos[idx[j] - idx[i] + 3]  (key minus query)
    float v = pos[(xj - xi + 3) * 7 + (yj - yi + 3)];
    if ((m & 1) && ((i >= 8) != (j >= 8))) v -= 1e9f;      // ul mask (last window row)
    if ((m & 2) && ((yi >= 2) != (yj >= 2))) v -= 1e9f;    // lr mask (last window col)
    biasT[t] = v;
  }
}

// ---------------- per-window LDS layout (f16 elements) ----------------
// QK: [16 tok][200]  feats 0..191 (q:0..95, k:96..191); after attn head h,
//     the PV output feats h*32..h*32+31 overwrite the (dead) q slots.
// VT: [96 vfeat][20] tokens 0..15
#define W_LDS 5120
#define QK_STRIDE 200
#define VT_STRIDE 20
#define VT_OFF 3200

__global__ __launch_bounds__(256, 4)
void swin_fused(const float* __restrict__ x,
                const _Float16* __restrict__ wqkvT,
                const _Float16* __restrict__ woutT,
                const float* __restrict__ biasT,
                const float* __restrict__ b_out,
                float* __restrict__ out) {
  __shared__ _Float16 lds[4 * W_LDS];
  const int tid  = threadIdx.x;
  const int wave = tid >> 6;
  const int lane = tid & 63;
  const int l15  = lane & 15;
  const int g    = (lane >> 4) & 3;
  const int ty = l15 >> 2, tx = l15 & 3;

  const int blk   = blockIdx.x;
  const int batch = blk / 196;
  const int wid0  = (blk % 196) * 4;   // 4 windows per block

  // ---- x fragments for the 4 windows (cyclic shift folded into address)
  half8_t xf[4][3];
#pragma unroll
  for (int wi = 0; wi < 4; ++wi) {
    int wid = wid0 + wi;
    int wrow = wid / 28, wcol = wid % 28;
    int p = wrow * 4 + ty + 2; if (p >= 112) p -= 112;
    int q = wcol * 4 + tx + 2; if (q >= 112) q -= 112;
    const float* xr = x + (((size_t)batch * 112 + p) * 112 + q) * 96 + g * 8;
#pragma unroll
    for (int kt = 0; kt < 3; ++kt) {
      float4_t a = *(const float4_t*)(xr + kt * 32);
      float4_t b = *(const float4_t*)(xr + kt * 32 + 4);
      half8_t h;
      h[0] = (_Float16)a[0]; h[1] = (_Float16)a[1];
      h[2] = (_Float16)a[2]; h[3] = (_Float16)a[3];
      h[4] = (_Float16)b[0]; h[5] = (_Float16)b[1];
      h[6] = (_Float16)b[2]; h[7] = (_Float16)b[3];
      xf[wi][kt] = h;
    }
  }

  // ---- GEMM1: feature tiles split across waves (W-frags shared over 4 windows)
  const int t0 = (wave * 18) >> 2;
  const int t1 = ((wave + 1) * 18) >> 2;
  for (int f = t0; f < t1; ++f) {
    const _Float16* wrow_p = &wqkvT[(f * 16 + l15) * 96 + g * 8];
    half8_t wf0 = *(const half8_t*)(wrow_p);
    half8_t wf1 = *(const half8_t*)(wrow_p + 32);
    half8_t wf2 = *(const half8_t*)(wrow_p + 64);
#pragma unroll
    for (int wi = 0; wi < 4; ++wi) {
      float4_t acc = {0.f, 0.f, 0.f, 0.f};
      half4_t hh;
      if (f < 12) {
        // D = WqkvT_slice @ x^T : row = feat f*16+4g+i, col = tok l15
        acc = __builtin_amdgcn_mfma_f32_16x16x32_f16(wf0, xf[wi][0], acc, 0, 0, 0);
        acc = __builtin_amdgcn_mfma_f32_16x16x32_f16(wf1, xf[wi][1], acc, 0, 0, 0);
        acc = __builtin_amdgcn_mfma_f32_16x16x32_f16(wf2, xf[wi][2], acc, 0, 0, 0);
        hh[0] = (_Float16)acc[0]; hh[1] = (_Float16)acc[1];
        hh[2] = (_Float16)acc[2]; hh[3] = (_Float16)acc[3];
        *(half4_t*)&lds[wi * W_LDS + l15 * QK_STRIDE + f * 16 + g * 4] = hh;
      } else {
        // D = x @ W_slice : row = tok 4g+i, col = feat -> vT[vfeat][tok]
        acc = __builtin_amdgcn_mfma_f32_16x16x32_f16(xf[wi][0], wf0, acc, 0, 0, 0);
        acc = __builtin_amdgcn_mfma_f32_16x16x32_f16(xf[wi][1], wf1, acc, 0, 0, 0);
        acc = __builtin_amdgcn_mfma_f32_16x16x32_f16(xf[wi][2], wf2, acc, 0, 0, 0);
        hh[0] = (_Float16)acc[0]; hh[1] = (_Float16)acc[1];
        hh[2] = (_Float16)acc[2]; hh[3] = (_Float16)acc[3];
        *(half4_t*)&lds[wi * W_LDS + VT_OFF + ((f - 12) * 16 + l15) * VT_STRIDE + g * 4] = hh;
      }
    }
  }
  __syncthreads();   // the only barrier: GEMM1 writes -> attn reads

  // ---- attention: wave w owns window w (everything below is same-wave)
  const int wid = wid0 + wave;
  const int wrow = wid / 28, wcol = wid % 28;
  _Float16* qk = &lds[wave * W_LDS];
  const _Float16* vt = &lds[wave * W_LDS + VT_OFF];
  {
    const int var = (wrow == 27 ? 1 : 0) + (wcol == 27 ? 2 : 0);
    const float* bt = biasT + var * 256 + g * 64 + l15;   // biasT[var][j=4g+i'][i=l15]
    const float b0 = bt[0], b1 = bt[16], b2 = bt[32], b3 = bt[48];
#pragma unroll
    for (int h = 0; h < 3; ++h) {
      // dots^T = K @ Q^T  (one 16x16x32 mfma; K = head_dim = 32)
      half8_t ak = *(const half8_t*)&qk[l15 * QK_STRIDE + 96 + h * 32 + g * 8];
      half8_t bq = *(const half8_t*)&qk[l15 * QK_STRIDE +      h * 32 + g * 8];
      float4_t dd = {0.f, 0.f, 0.f, 0.f};
      dd = __builtin_amdgcn_mfma_f32_16x16x32_f16(ak, bq, dd, 0, 0, 0);
      const float scale = 0.17677669529663687f;  // 32^-0.5
      float dv0 = dd[0] * scale + b0;
      float dv1 = dd[1] * scale + b1;
      float dv2 = dd[2] * scale + b2;
      float dv3 = dd[3] * scale + b3;
      // softmax over keys j (4 regs + lane-groups): col i fixed per lane
      float mx = fmaxf(fmaxf(dv0, dv1), fmaxf(dv2, dv3));
      mx = fmaxf(mx, __shfl_xor(mx, 16, 64));
      mx = fmaxf(mx, __shfl_xor(mx, 32, 64));
      float p0 = __expf(dv0 - mx), p1 = __expf(dv1 - mx);
      float p2 = __expf(dv2 - mx), p3 = __expf(dv3 - mx);
      float s = p0 + p1 + p2 + p3;
      s += __shfl_xor(s, 16, 64);
      s += __shfl_xor(s, 32, 64);
      float r = 1.0f / s;
      half4_t pb;   // P^T in D-layout == valid B-operand of 16x16x16 mfma
      pb[0] = (_Float16)(p0 * r); pb[1] = (_Float16)(p1 * r);
      pb[2] = (_Float16)(p2 * r); pb[3] = (_Float16)(p3 * r);
#pragma unroll
      for (int db = 0; db < 2; ++db) {
        // out^T[dblock] = v^T[dblock] @ P^T   (16x16, K=16 tokens)
        half4_t av = *(const half4_t*)&vt[(h * 32 + db * 16 + l15) * VT_STRIDE + g * 4];
        float4_t o = {0.f, 0.f, 0.f, 0.f};
        o = __builtin_amdgcn_mfma_f32_16x16x16f16(av, pb, o, 0, 0, 0);
        half4_t oh;
        oh[0] = (_Float16)o[0]; oh[1] = (_Float16)o[1];
        oh[2] = (_Float16)o[2]; oh[3] = (_Float16)o[3];
        // overwrite the (now dead) q slots of head h with attn output feats
        *(half4_t*)&qk[l15 * QK_STRIDE + h * 32 + db * 16 + g * 4] = oh;
      }
    }
  }

  // ---- GEMM3 (same wave, no barrier): y = WoutT @ out^T + b, inverse roll in store
  {
    half8_t bf0 = *(const half8_t*)&qk[l15 * QK_STRIDE +      g * 8];
    half8_t bf1 = *(const half8_t*)&qk[l15 * QK_STRIDE + 32 + g * 8];
    half8_t bf2 = *(const half8_t*)&qk[l15 * QK_STRIDE + 64 + g * 8];
    int p = wrow * 4 + ty + 2; if (p >= 112) p -= 112;
    int q = wcol * 4 + tx + 2; if (q >= 112) q -= 112;
    float* orow = out + (((size_t)batch * 112 + p) * 112 + q) * 96;
#pragma unroll
    for (int mt = 0; mt < 6; ++mt) {
      const _Float16* wo = &woutT[(mt * 16 + l15) * 96 + g * 8];
      half8_t w0 = *(const half8_t*)(wo);
      half8_t w1 = *(const half8_t*)(wo + 32);
      half8_t w2 = *(const half8_t*)(wo + 64);
      float4_t acc = {0.f, 0.f, 0.f, 0.f};
      acc = __builtin_amdgcn_mfma_f32_16x16x32_f16(w0, bf0, acc, 0, 0, 0);
      acc = __builtin_amdgcn_mfma_f32_16x16x32_f16(w1, bf1, acc, 0, 0, 0);
      acc = __builtin_amdgcn_mfma_f32_16x16x32_f16(w2, bf2, acc, 0, 0, 0);
      float4_t bb = *(const float4_t*)&b_out[mt * 16 + g * 4];
      acc[0] += bb[0]; acc[1] += bb[1]; acc[2] += bb[2]; acc[3] += bb[3];
      *(float4_t*)&orow[mt * 16 + g * 4] = acc;
    }
  }
}

extern "C" void kernel_launch(void* const* d_in, const int* in_sizes, int n_in,
                              void* d_out, int out_size, void* d_ws, size_t ws_size,
                              hipStream_t stream) {
  const float* x    = (const float*)d_in[0];
  const float* Wqkv = (const float*)d_in[1];
  const float* pos  = (const float*)d_in[2];
  const float* Wout = (const float*)d_in[3];
  const float* bout = (const float*)d_in[4];
  char* ws = (char*)d_ws;
  _Float16* wqkvT = (_Float16*)ws;
  _Float16* woutT = ((_Float16*)ws) + WOUTT_OFF_H;
  float* biasT = (float*)(ws + BIAST_OFF_B);

  prep_kernel<<<148, 256, 0, stream>>>(Wqkv, Wout, pos, wqkvT, woutT, biasT);
  swin_fused<<<6272, 256, 0, stream>>>(x, wqkvT, woutT, biasT, bout, (float*)d_out);
}